// Round 5
// baseline (544.085 us; speedup 1.0000x reference)
//
#include <hip/hip_runtime.h>
#include <hip/hip_cooperative_groups.h>

namespace cg = cooperative_groups;

// Problem constants (PointPillarsScatter)
#define NB 4
#define NC 64
#define NH 282
#define NW 282
#define NP 12000
#define HWC (NH * NW)          // 79524, divisible by 4
#define QHW (HWC / 4)          // 19881 int4/float4 per channel plane
#define CLAIM_INTS (NB * HWC)  // 318096 ints = 1.27 MB
#define NBLK 2048              // 8 blocks/CU x 256 CUs -> co-resident
#define NTHR 256
#define TOTTHR (NBLK * NTHR)   // 524288 threads

// Claim map in a device global (known-good since r3).
__device__ __align__(16) int g_claim[CLAIM_INTS];

using f4v = __attribute__((ext_vector_type(4))) float;

// Single cooperative kernel: init -> sync -> claim -> sync -> fill.
// Phase B grid math bit-matches the XLA:CPU golden (/0.16 rewritten to
// *6.25f; r3/r4: absmax = 0.0). atomicMax(p) == last-write-wins.
__global__ __launch_bounds__(NTHR, 8) void pps_fused_kernel(
        const float* __restrict__ pfn_in,
        const float* __restrict__ pfn_out,
        float4* __restrict__ out) {
    cg::grid_group grid = cg::this_grid();
    const int tid = blockIdx.x * NTHR + threadIdx.x;

    // --- Phase A: claim = -1 everywhere (one int4 store per thread) ---
    for (int i = tid; i < CLAIM_INTS / 4; i += TOTTHR) {
        ((int4*)g_claim)[i] = make_int4(-1, -1, -1, -1);
    }

    grid.sync();

    // --- Phase B: valid points claim their cell with atomicMax(p) ---
    if (tid < NB * NP) {
        int b = tid / NP;
        int p = tid - b * NP;
        const float* base = pfn_in + (size_t)b * 2 * NP;   // [b][2][P][1]
        float x = base[p];
        if (x != 0.0f) {                     // x==0 -> invalid -> dropped
            float y = base[NP + p];
            int xg = (int)floorf((x + 22.0f) * 6.25f);
            int yg = (int)floorf((y + 22.0f) * 6.25f);
            xg = min(max(xg, 0), NW - 1);
            yg = min(max(yg, 0), NH - 1);
            atomicMax(&g_claim[b * HWC + yg * NW + xg], p);
        }
    }

    grid.sync();

    // --- Phase C: gather-fill, grid-stride (~10 float4/thread for ILP) ---
    // Claim reads are L2-hot (1.27 MB unique, read 64x). ~89% of cells are
    // empty -> no gather load at all. Output written nontemporal so the
    // 81.4 MB write stream doesn't evict the small L2 read set.
    const int total = NB * NC * QHW;         // 5,089,536 float4s
    for (int gid = tid; gid < total; gid += TOTTHR) {
        int plane = gid / QHW;               // b*NC + c
        int q = gid - plane * QHW;
        int b = plane >> 6;                  // NC == 64
        int4 c4 = ((const int4*)(g_claim + b * HWC))[q];
        const float* row = pfn_out + (size_t)plane * NP;   // PFN_output[b][c][:]
        float4 v;
        v.x = (c4.x >= 0) ? row[c4.x] : 0.0f;
        v.y = (c4.y >= 0) ? row[c4.y] : 0.0f;
        v.z = (c4.z >= 0) ? row[c4.z] : 0.0f;
        v.w = (c4.w >= 0) ? row[c4.w] : 0.0f;
        __builtin_nontemporal_store(*(const f4v*)&v, (f4v*)&out[gid]);
    }
}

extern "C" void kernel_launch(void* const* d_in, const int* in_sizes, int n_in,
                              void* d_out, int out_size, void* d_ws, size_t ws_size,
                              hipStream_t stream) {
    const float* pfn_in  = (const float*)d_in[0];   // (4, 2, 12000, 1) f32
    const float* pfn_out = (const float*)d_in[1];   // (4, 64, 12000)   f32
    float4* out = (float4*)d_out;                   // (4, 64, 282, 282) f32
    (void)d_ws; (void)ws_size;

    void* args[] = {(void*)&pfn_in, (void*)&pfn_out, (void*)&out};
    hipLaunchCooperativeKernel((const void*)pps_fused_kernel,
                               dim3(NBLK), dim3(NTHR), args, 0, stream);
}

// Round 6
// 119.674 us; speedup vs baseline: 4.5464x; 4.5464x over previous
//
#include <hip/hip_runtime.h>

// Problem constants (PointPillarsScatter)
#define NB 4
#define NC 64
#define NH 282
#define NW 282
#define NP 12000
#define HWC (NH * NW)          // 79524, divisible by 4
#define QHW (HWC / 4)          // 19881 int4/float4 per channel plane
#define CLAIM_INTS (NB * HWC)  // 318096 ints = 1.27 MB
#define UNROLL 4
#define FBLK 256
#define CHUNK (FBLK * UNROLL)  // 1024 float4 per block
#define NXBLK ((QHW + CHUNK - 1) / CHUNK)   // 20

// Claim map in a device global (known-good since r3).
__device__ __align__(16) int g_claim[CLAIM_INTS];

// Pass 0: claim = -1 everywhere (vectorized int4 stores). ~0.5 us.
__global__ void pps_init_kernel() {
    int gid = blockIdx.x * blockDim.x + threadIdx.x;
    if (gid < CLAIM_INTS / 4) {
        ((int4*)g_claim)[gid] = make_int4(-1, -1, -1, -1);
    }
}

// Pass 1: each valid point claims its cell with atomicMax(point index).
// Last-write-wins == highest p wins. Grid index bit-matches the XLA:CPU
// golden: /0.16 is rewritten to *(1/0.16f) == *6.25f (r3/r4: absmax = 0.0).
__global__ void pps_claim_kernel(const float* __restrict__ pfn_in) {
    int gid = blockIdx.x * blockDim.x + threadIdx.x;
    if (gid >= NB * NP) return;
    int b = gid / NP;
    int p = gid - b * NP;
    const float* base = pfn_in + (size_t)b * 2 * NP;  // [b][2][P][1]
    float x = base[p];
    if (x == 0.0f) return;                      // invalid -> OOB in ref -> dropped
    float y = base[NP + p];
    int xg = (int)floorf((x + 22.0f) * 6.25f);
    int yg = (int)floorf((y + 22.0f) * 6.25f);
    xg = min(max(xg, 0), NW - 1);
    yg = min(max(yg, 0), NH - 1);
    atomicMax(&g_claim[b * HWC + yg * NW + xg], p);
}

// Pass 2 (v3): gather fill with 4 independent units per thread.
// grid = (20 q-chunks, 256 planes). All 4 int4 claim loads issue before any
// dependent gather -> 4x memory-level parallelism per thread vs r3. No
// per-thread division. Claim reads are L2-hot (<=2 batches * 318 KB live at
// once given block order); ~89% of cells are empty -> no gather load.
// Regular cached float4 stores (write-combine through L2; nt was the r5
// disaster: 175 GB/s uncombined stream).
__global__ __launch_bounds__(FBLK) void pps_fill3_kernel(
        const float* __restrict__ pfn_out, float4* __restrict__ out) {
    const int plane = blockIdx.y;                 // b*NC + c
    const int b = plane >> 6;                     // NC == 64
    const int q0 = blockIdx.x * CHUNK + threadIdx.x;
    const int4* __restrict__ cl = (const int4*)(g_claim + b * HWC);
    const float* __restrict__ row = pfn_out + (size_t)plane * NP;
    float4* __restrict__ dst = out + (size_t)plane * QHW;

    int4 c[UNROLL];
    #pragma unroll
    for (int k = 0; k < UNROLL; ++k) {
        int q = q0 + k * FBLK;
        if (q < QHW) c[k] = cl[q];                // 4 loads in flight
    }
    #pragma unroll
    for (int k = 0; k < UNROLL; ++k) {
        int q = q0 + k * FBLK;
        if (q < QHW) {
            int4 c4 = c[k];
            float4 v;
            v.x = (c4.x >= 0) ? row[c4.x] : 0.0f;
            v.y = (c4.y >= 0) ? row[c4.y] : 0.0f;
            v.z = (c4.z >= 0) ? row[c4.z] : 0.0f;
            v.w = (c4.w >= 0) ? row[c4.w] : 0.0f;
            dst[q] = v;
        }
    }
}

extern "C" void kernel_launch(void* const* d_in, const int* in_sizes, int n_in,
                              void* d_out, int out_size, void* d_ws, size_t ws_size,
                              hipStream_t stream) {
    const float* pfn_in  = (const float*)d_in[0];   // (4, 2, 12000, 1) f32
    const float* pfn_out = (const float*)d_in[1];   // (4, 64, 12000)   f32
    float4* out = (float4*)d_out;                   // (4, 64, 282, 282) f32
    (void)d_ws; (void)ws_size;

    {
        int total = CLAIM_INTS / 4;      // 79524 int4 stores
        pps_init_kernel<<<(total + 255) / 256, 256, 0, stream>>>();
    }
    {
        int total = NB * NP;             // 48000 points
        pps_claim_kernel<<<(total + 255) / 256, 256, 0, stream>>>(pfn_in);
    }
    {
        dim3 grid(NXBLK, NB * NC);       // (20, 256) = 5120 blocks
        pps_fill3_kernel<<<grid, FBLK, 0, stream>>>(pfn_out, out);
    }
}